// Round 1
// baseline (486.916 us; speedup 1.0000x reference)
//
#include <hip/hip_runtime.h>
#include <hip/hip_bf16.h>
#include <stdint.h>

// Problem constants
#define BB   32
#define CIN  256
#define COUT 256
#define HH   56
#define WW   56
#define HW   3136           // 56*56
#define KEXP 4

typedef __attribute__((ext_vector_type(8))) short  short8;
typedef __attribute__((ext_vector_type(4))) float  floatx4;

struct __align__(8) US4 { unsigned short x, y, z, w; };

__device__ __forceinline__ unsigned short f2bf(float f) {
    uint32_t u = __float_as_uint(f);
    u = (u + 0x7fffu + ((u >> 16) & 1u)) >> 16;
    return (unsigned short)u;
}
__device__ __forceinline__ float bf2f(unsigned short s) {
    return __uint_as_float(((uint32_t)s) << 16);
}

__device__ __forceinline__ void async_copy16(const void* gsrc, void* ldst) {
    __builtin_amdgcn_global_load_lds(
        (const __attribute__((address_space(1))) unsigned int*)gsrc,
        (__attribute__((address_space(3))) unsigned int*)ldst, 16, 0, 0);
}

// ---------------------------------------------------------------------------
// Kernel T: NCHW fp32 -> NHWC bf16 transpose, fused global-avg-pool partial
// grid: B*H blocks (one (b,h) row each), 256 threads
// ---------------------------------------------------------------------------
__global__ __launch_bounds__(256) void transpose_pool_kernel(
    const float* __restrict__ x,          // [B][CIN][H][W]
    unsigned short* __restrict__ xt,      // [B][H][W][CIN] bf16
    float* __restrict__ pooled)           // [B][CIN], pre-zeroed
{
    __shared__ unsigned short tile[CIN * WW];   // [c][w], 28 KB
    const int bx  = blockIdx.x;
    const int b   = bx / HH;
    const int h   = bx % HH;
    const int tid = threadIdx.x;

    const float* xb = x + (size_t)b * CIN * HW + h * WW;

    // stage: 256 channels x 14 float4 (56 floats per row)
    for (int i = tid; i < CIN * 14; i += 256) {
        const int c  = i / 14;
        const int wv = i % 14;
        const float4 v = *(const float4*)(xb + (size_t)c * HW + wv * 4);
        US4 u;
        u.x = f2bf(v.x); u.y = f2bf(v.y); u.z = f2bf(v.z); u.w = f2bf(v.w);
        *(US4*)&tile[c * WW + wv * 4] = u;
    }
    __syncthreads();

    // per-channel partial row sum -> pooled (mean accumulated via atomics)
    {
        const int c = tid;
        float s = 0.f;
        #pragma unroll 8
        for (int i = 0; i < WW; ++i) s += bf2f(tile[c * WW + i]);
        atomicAdd(&pooled[b * CIN + c], s * (1.0f / (float)HW));
    }

    // write NHWC: consecutive threads -> consecutive c (coalesced)
    for (int j = tid; j < WW * CIN; j += 256) {
        const int w = j >> 8;
        const int c = j & 255;
        xt[(((size_t)b * HH + h) * WW + w) * CIN + c] = tile[c * WW + w];
    }
}

// ---------------------------------------------------------------------------
// Kernel A: attention MLP + softmax  -> att[B][K]
// 1 block, 64 threads (thread b handles sample b)
// ---------------------------------------------------------------------------
__global__ __launch_bounds__(64) void attn_kernel(
    const float* __restrict__ pooled,   // [B][CIN]
    const float* __restrict__ fc1w,     // [K][CIN]
    const float* __restrict__ fc1b,     // [K]
    const float* __restrict__ fc2w,     // [K][K]
    const float* __restrict__ fc2b,     // [K]
    float* __restrict__ att)            // [B][K]
{
    const int b = threadIdx.x;
    if (b >= BB) return;
    const float* pb = pooled + b * CIN;
    float a[KEXP];
    #pragma unroll
    for (int k = 0; k < KEXP; ++k) {
        float s = fc1b[k];
        const float* w = fc1w + k * CIN;
        for (int c = 0; c < CIN; ++c) s += pb[c] * w[c];
        a[k] = fmaxf(s, 0.f);
    }
    float z[KEXP], m = -1e30f;
    #pragma unroll
    for (int j = 0; j < KEXP; ++j) {
        float s = fc2b[j];
        #pragma unroll
        for (int k = 0; k < KEXP; ++k) s += a[k] * fc2w[j * KEXP + k];
        z[j] = s;
        m = fmaxf(m, s);
    }
    float den = 0.f;
    #pragma unroll
    for (int j = 0; j < KEXP; ++j) { z[j] = expf(z[j] - m); den += z[j]; }
    const float inv = 1.0f / den;
    #pragma unroll
    for (int j = 0; j < KEXP; ++j) att[b * KEXP + j] = z[j] * inv;
}

// ---------------------------------------------------------------------------
// Kernel W: aggregate expert weights -> agg_w[b][rs][o][c] (bf16), agg_b[b][o]
// grid: B*COUT blocks (one (b,o) each), 256 threads
// ---------------------------------------------------------------------------
__global__ __launch_bounds__(256) void aggw_kernel(
    const float* __restrict__ weight,   // [K][COUT][CIN][3][3]
    const float* __restrict__ bias,     // [K][COUT]
    const float* __restrict__ att,      // [B][K]
    unsigned short* __restrict__ aggw,  // [B][9][COUT][CIN] bf16
    float* __restrict__ aggb)           // [B][COUT]
{
    __shared__ float accw[CIN * 9];     // linear i = c*9 + rs, 9216 B
    const int bx  = blockIdx.x;
    const int b   = bx >> 8;
    const int o   = bx & 255;
    const int tid = threadIdx.x;

    float av[KEXP];
    #pragma unroll
    for (int k = 0; k < KEXP; ++k) av[k] = att[b * KEXP + k];

    float r[9];
    #pragma unroll
    for (int j = 0; j < 9; ++j) r[j] = 0.f;
    #pragma unroll
    for (int k = 0; k < KEXP; ++k) {
        const float* wk = weight + (size_t)(k * COUT + o) * (CIN * 9);
        #pragma unroll
        for (int j = 0; j < 9; ++j) r[j] += av[k] * wk[j * 256 + tid];
    }
    #pragma unroll
    for (int j = 0; j < 9; ++j) accw[j * 256 + tid] = r[j];
    __syncthreads();

    // transpose (c,rs) -> (rs,c); LDS read stride 9 dwords: conflict-free
    #pragma unroll
    for (int j = 0; j < 9; ++j) {
        const float v = accw[tid * 9 + j];
        aggw[(((size_t)b * 9 + j) * COUT + o) * CIN + tid] = f2bf(v);
    }
    if (tid == 0) {
        float s = 0.f;
        #pragma unroll
        for (int k = 0; k < KEXP; ++k) s += av[k] * bias[k * COUT + o];
        aggb[b * COUT + o] = s;
    }
}

// ---------------------------------------------------------------------------
// Kernel G: per-sample implicit-im2col GEMM (m97 structure)
// C[o][p] += A[o][c]*B[c][p] over 36 K-iters (9 taps x 4 chunks of 64 ch)
// grid: B * 2 (o-tiles) * 25 (p-tiles) = 1600 blocks, 256 threads (4 waves)
// ---------------------------------------------------------------------------
__global__ __launch_bounds__(256) void conv_gemm_kernel(
    const unsigned short* __restrict__ xt,    // [B][HW][CIN] bf16 (NHWC)
    const unsigned short* __restrict__ aggw,  // [B][9][COUT][CIN] bf16
    const float* __restrict__ aggb,           // [B][COUT]
    const unsigned short* __restrict__ zbuf,  // >=256 B of zeros
    float* __restrict__ out)                  // [B][COUT][HW]
{
    __shared__ unsigned short As[128 * 64];   // [o_local][c] 16 KB
    __shared__ unsigned short Bs[128 * 64];   // [p_local][c] 16 KB

    const int bx = blockIdx.x;
    const int b  = bx / 50;
    const int rr = bx % 50;
    const int ot = rr / 25;
    const int pt = rr % 25;
    const int o0 = ot * 128;
    const int p0 = pt * 128;

    const int tid    = threadIdx.x;
    const int wave   = tid >> 6;
    const int lane   = tid & 63;
    const int lrow   = lane >> 3;          // 0..7
    const int lchunk = (lane & 7) * 16;    // byte offset within 128 B row

    const char* aggw_b = (const char*)aggw + (size_t)b * 9 * COUT * CIN * 2;
    const char* xt_b   = (const char*)xt   + (size_t)b * HW * CIN * 2;
    const char* zb     = (const char*)zbuf;

    // Per-issue fixed offsets. Issue j covers rows j*32 + wave*8 + lrow.
    int aoff[4];
    int boff[4], bh[4], bw[4], bval[4];
    #pragma unroll
    for (int j = 0; j < 4; ++j) {
        const int rowl = j * 32 + wave * 8 + lrow;
        aoff[j] = (o0 + rowl) * 512 + lchunk;
        const int p = p0 + rowl;
        bh[j]   = p / 56;
        bw[j]   = p % 56;
        bval[j] = (p < HW);
        boff[j] = p * 512 + lchunk;        // (h*56+w)*CIN*2 + chunk
    }

    floatx4 acc[4][4];
    #pragma unroll
    for (int mi = 0; mi < 4; ++mi)
        #pragma unroll
        for (int ni = 0; ni < 4; ++ni)
            #pragma unroll
            for (int i = 0; i < 4; ++i) acc[mi][ni][i] = 0.f;

    const int row_base = (wave >> 1) * 64;
    const int col_base = (wave & 1) * 64;
    const int m_off    = lane & 15;
    const int g8       = (lane >> 4) * 8;

    for (int kt = 0; kt < 36; ++kt) {
        const int rs = kt >> 2;
        const int c0 = (kt & 3) * 64;
        const int dh = rs / 3 - 1;
        const int dw = rs % 3 - 1;

        const int a_kt = rs * (COUT * CIN * 2) + c0 * 2;   // uniform
        const int b_kt = (dh * 56 + dw) * 512 + c0 * 2;    // uniform

        #pragma unroll
        for (int j = 0; j < 4; ++j) {
            async_copy16(aggw_b + (size_t)(aoff[j] + a_kt),
                         &As[(j * 32 + wave * 8) * 64]);
        }
        #pragma unroll
        for (int j = 0; j < 4; ++j) {
            const int h2 = bh[j] + dh;
            const int w2 = bw[j] + dw;
            const bool ok = bval[j] && ((unsigned)h2 < 56u) && ((unsigned)w2 < 56u);
            const char* src = ok ? (xt_b + (size_t)(boff[j] + b_kt))
                                 : (zb + lchunk);
            async_copy16(src, &Bs[(j * 32 + wave * 8) * 64]);
        }
        __syncthreads();   // drains vmcnt(0): LDS tiles ready

        #pragma unroll
        for (int ks = 0; ks < 2; ++ks) {
            short8 af[4], bf[4];
            #pragma unroll
            for (int mi = 0; mi < 4; ++mi)
                af[mi] = *(const short8*)&As[(row_base + mi * 16 + m_off) * 64 + ks * 32 + g8];
            #pragma unroll
            for (int ni = 0; ni < 4; ++ni)
                bf[ni] = *(const short8*)&Bs[(col_base + ni * 16 + m_off) * 64 + ks * 32 + g8];
            #pragma unroll
            for (int mi = 0; mi < 4; ++mi)
                #pragma unroll
                for (int ni = 0; ni < 4; ++ni)
                    acc[mi][ni] = __builtin_amdgcn_mfma_f32_16x16x32_bf16(
                        af[mi], bf[ni], acc[mi][ni], 0, 0, 0);
        }
        __syncthreads();   // all waves done reading before next stage
    }

    // Epilogue: C/D layout col = lane&15, row = (lane>>4)*4 + i
    float* outb = out + (size_t)b * COUT * HW;
    const int g4 = (lane >> 4) * 4;
    #pragma unroll
    for (int mi = 0; mi < 4; ++mi) {
        #pragma unroll
        for (int i = 0; i < 4; ++i) {
            const int o = o0 + row_base + mi * 16 + g4 + i;
            const float bv = aggb[b * COUT + o];
            #pragma unroll
            for (int ni = 0; ni < 4; ++ni) {
                const int p = p0 + col_base + ni * 16 + m_off;
                if (p < HW) outb[(size_t)o * HW + p] = acc[mi][ni][i] + bv;
            }
        }
    }
}

// ---------------------------------------------------------------------------
// Launch
// ---------------------------------------------------------------------------
extern "C" void kernel_launch(void* const* d_in, const int* in_sizes, int n_in,
                              void* d_out, int out_size, void* d_ws, size_t ws_size,
                              hipStream_t stream) {
    const float* x      = (const float*)d_in[0];
    const float* weight = (const float*)d_in[1];
    const float* bias   = (const float*)d_in[2];
    const float* fc1w   = (const float*)d_in[3];
    const float* fc1b   = (const float*)d_in[4];
    const float* fc2w   = (const float*)d_in[5];
    const float* fc2b   = (const float*)d_in[6];
    float* out = (float*)d_out;

    char* ws = (char*)d_ws;
    // workspace layout (all 256 B aligned)
    unsigned short* xt     = (unsigned short*)(ws);              // 51,380,224 B
    unsigned short* aggw   = (unsigned short*)(ws + 51380224);   // 37,748,736 B
    float*          pooled = (float*)(ws + 89128960);            //     32,768 B
    float*          att    = (float*)(ws + 89161728);            //        512 B
    float*          aggb   = (float*)(ws + 89162240);            //     32,768 B
    unsigned short* zbuf   = (unsigned short*)(ws + 89195008);   //        256 B

    hipMemsetAsync((void*)pooled, 0, 32768, stream);
    hipMemsetAsync((void*)zbuf,   0, 256,   stream);

    transpose_pool_kernel<<<BB * HH, 256, 0, stream>>>(x, xt, pooled);
    attn_kernel<<<1, 64, 0, stream>>>(pooled, fc1w, fc1b, fc2w, fc2b, att);
    aggw_kernel<<<BB * COUT, 256, 0, stream>>>(weight, bias, att, aggw, aggb);
    conv_gemm_kernel<<<BB * 2 * 25, 256, 0, stream>>>(xt, aggw, aggb, zbuf, out);
}

// Round 2
// 403.214 us; speedup vs baseline: 1.2076x; 1.2076x over previous
//
#include <hip/hip_runtime.h>
#include <hip/hip_bf16.h>
#include <stdint.h>

// Problem constants
#define BB   32
#define CIN  256
#define COUT 256
#define HH   56
#define WW   56
#define HW   3136           // 56*56
#define KEXP 4

typedef __attribute__((ext_vector_type(8))) short  short8;
typedef __attribute__((ext_vector_type(4))) float  floatx4;

__device__ __forceinline__ unsigned short f2bf(float f) {
    uint32_t u = __float_as_uint(f);
    u = (u + 0x7fffu + ((u >> 16) & 1u)) >> 16;
    return (unsigned short)u;
}
__device__ __forceinline__ float bf2f(unsigned short s) {
    return __uint_as_float(((uint32_t)s) << 16);
}
__device__ __forceinline__ uint32_t pack2(float a, float b) {
    return (uint32_t)f2bf(a) | ((uint32_t)f2bf(b) << 16);
}

__device__ __forceinline__ void async_copy16(const void* gsrc, void* ldst) {
    __builtin_amdgcn_global_load_lds(
        (const __attribute__((address_space(1))) unsigned int*)gsrc,
        (__attribute__((address_space(3))) unsigned int*)ldst, 16, 0, 0);
}

// ---------------------------------------------------------------------------
// Kernel T: NCHW fp32 -> NHWC bf16 transpose, fused global-avg-pool partial
// grid: B*H blocks (one (b,h) row each), 256 threads
// LDS tile [c][w] with row stride 62 elements (124 B): bank step per c is
// 31 dwords -> gcd(31,32)=1 -> read-back (c-fast lanes) ~conflict-free;
// dword-aligned for all c (124 % 4 == 0).
// ---------------------------------------------------------------------------
__global__ __launch_bounds__(256) void transpose_pool_kernel(
    const float* __restrict__ x,          // [B][CIN][H][W]
    unsigned short* __restrict__ xt,      // [B][H][W][CIN] bf16
    float* __restrict__ pooled)           // [B][CIN], pre-zeroed
{
    __shared__ unsigned short tile[CIN * 62];   // 31,744 B
    const int bx  = blockIdx.x;
    const int b   = bx / HH;
    const int h   = bx % HH;
    const int tid = threadIdx.x;

    const float* xb = x + (size_t)b * CIN * HW + h * WW;

    // stage: 256 channels x 14 float4 (56 floats per row)
    for (int i = tid; i < CIN * 14; i += 256) {
        const int c  = i / 14;
        const int wv = i % 14;
        const float4 v = *(const float4*)(xb + (size_t)c * HW + wv * 4);
        uint32_t* p = (uint32_t*)&tile[c * 62 + wv * 4];
        p[0] = pack2(v.x, v.y);
        p[1] = pack2(v.z, v.w);
    }
    __syncthreads();

    // per-channel partial row sum -> pooled (mean accumulated via atomics)
    {
        const int c = tid;
        float s = 0.f;
        #pragma unroll 8
        for (int i = 0; i < WW; ++i) s += bf2f(tile[c * 62 + i]);
        atomicAdd(&pooled[b * CIN + c], s * (1.0f / (float)HW));
    }

    // write NHWC: consecutive threads -> consecutive c (coalesced)
    for (int j = tid; j < WW * CIN; j += 256) {
        const int w = j >> 8;
        const int c = j & 255;
        xt[(((size_t)b * HH + h) * WW + w) * CIN + c] = tile[c * 62 + w];
    }
}

// ---------------------------------------------------------------------------
// Kernel A: attention MLP + softmax  -> att[B][K]
// grid: B blocks x 64 lanes; lane-parallel dot products + shuffle reduce
// ---------------------------------------------------------------------------
__global__ __launch_bounds__(64) void attn_kernel(
    const float* __restrict__ pooled,   // [B][CIN]
    const float* __restrict__ fc1w,     // [K][CIN]
    const float* __restrict__ fc1b,     // [K]
    const float* __restrict__ fc2w,     // [K][K]
    const float* __restrict__ fc2b,     // [K]
    float* __restrict__ att)            // [B][K]
{
    const int b    = blockIdx.x;
    const int lane = threadIdx.x;
    const float* pb = pooled + b * CIN;

    float s[KEXP] = {0.f, 0.f, 0.f, 0.f};
    #pragma unroll
    for (int c0 = 0; c0 < CIN; c0 += 64) {
        const float p = pb[c0 + lane];
        #pragma unroll
        for (int k = 0; k < KEXP; ++k) s[k] += p * fc1w[k * CIN + c0 + lane];
    }
    #pragma unroll
    for (int off = 32; off > 0; off >>= 1) {
        #pragma unroll
        for (int k = 0; k < KEXP; ++k) s[k] += __shfl_down(s[k], off);
    }
    if (lane == 0) {
        float a[KEXP];
        #pragma unroll
        for (int k = 0; k < KEXP; ++k) a[k] = fmaxf(s[k] + fc1b[k], 0.f);
        float z[KEXP], m = -1e30f;
        #pragma unroll
        for (int j = 0; j < KEXP; ++j) {
            float t = fc2b[j];
            #pragma unroll
            for (int k = 0; k < KEXP; ++k) t += a[k] * fc2w[j * KEXP + k];
            z[j] = t;
            m = fmaxf(m, t);
        }
        float den = 0.f;
        #pragma unroll
        for (int j = 0; j < KEXP; ++j) { z[j] = expf(z[j] - m); den += z[j]; }
        const float inv = 1.0f / den;
        #pragma unroll
        for (int j = 0; j < KEXP; ++j) att[b * KEXP + j] = z[j] * inv;
    }
}

// ---------------------------------------------------------------------------
// Kernel W: aggregate expert weights -> agg_w[b][rs][o][c] (bf16), agg_b[b][o]
// grid: B*COUT blocks (one (b,o) each), 256 threads
// ---------------------------------------------------------------------------
__global__ __launch_bounds__(256) void aggw_kernel(
    const float* __restrict__ weight,   // [K][COUT][CIN][3][3]
    const float* __restrict__ bias,     // [K][COUT]
    const float* __restrict__ att,      // [B][K]
    unsigned short* __restrict__ aggw,  // [B][9][COUT][CIN] bf16
    float* __restrict__ aggb)           // [B][COUT]
{
    __shared__ float accw[CIN * 9];     // linear i = rs*256 + c
    const int bx  = blockIdx.x;
    const int b   = bx >> 8;
    const int o   = bx & 255;
    const int tid = threadIdx.x;

    float av[KEXP];
    #pragma unroll
    for (int k = 0; k < KEXP; ++k) av[k] = att[b * KEXP + k];

    float r[9];
    #pragma unroll
    for (int j = 0; j < 9; ++j) r[j] = 0.f;
    #pragma unroll
    for (int k = 0; k < KEXP; ++k) {
        const float* wk = weight + (size_t)(k * COUT + o) * (CIN * 9);
        #pragma unroll
        for (int j = 0; j < 9; ++j) r[j] += av[k] * wk[j * 256 + tid];
    }
    #pragma unroll
    for (int j = 0; j < 9; ++j) accw[j * 256 + tid] = r[j];
    __syncthreads();

    // transpose (c,rs) -> (rs,c); LDS read stride 9 dwords: conflict-free
    #pragma unroll
    for (int j = 0; j < 9; ++j) {
        const float v = accw[tid * 9 + j];
        aggw[(((size_t)b * 9 + j) * COUT + o) * CIN + tid] = f2bf(v);
    }
    if (tid == 0) {
        float s = 0.f;
        #pragma unroll
        for (int k = 0; k < KEXP; ++k) s += av[k] * bias[k * COUT + o];
        aggb[b * COUT + o] = s;
    }
}

// ---------------------------------------------------------------------------
// Kernel G: per-sample implicit-im2col GEMM (m97 structure)
// C[o][p] += A[o][c]*B[c][p] over 36 K-iters (9 taps x 4 chunks of 64 ch)
// grid: B * 2 (o-tiles) * 25 (p-tiles) = 1600 blocks, 256 threads (4 waves)
//
// XCD-affinity swizzle: dispatch round-robins blockIdx % 8 across XCDs, so
// map sample b -> XCD b%8. Per-sample working set (xt 1.6 MB + aggw 1.18 MB)
// fits one XCD's 4 MB L2.
//
// LDS XOR swizzle: physical 16B-unit = logical_unit ^ (row & 7). Write side
// (global_load_lds dest is pinned to base+lane*16) applies the inverse
// permutation on the GLOBAL source address instead.
// ---------------------------------------------------------------------------
__global__ __launch_bounds__(256) void conv_gemm_kernel(
    const unsigned short* __restrict__ xt,    // [B][HW][CIN] bf16 (NHWC)
    const unsigned short* __restrict__ aggw,  // [B][9][COUT][CIN] bf16
    const float* __restrict__ aggb,           // [B][COUT]
    const unsigned short* __restrict__ zbuf,  // >=256 B of zeros
    float* __restrict__ out)                  // [B][COUT][HW]
{
    __shared__ unsigned short As[128 * 64];   // [o_local][c] 16 KB, swizzled
    __shared__ unsigned short Bs[128 * 64];   // [p_local][c] 16 KB, swizzled

    const int bx   = blockIdx.x;
    const int slot = bx >> 3;          // 0..199 within an XCD
    const int xcd  = bx & 7;
    const int b    = xcd + 8 * (slot / 50);
    const int rr   = slot % 50;
    const int pt   = rr >> 1;          // ot-pairs adjacent: share B tile in L2
    const int ot   = rr & 1;
    const int o0   = ot * 128;
    const int p0   = pt * 128;

    const int tid  = threadIdx.x;
    const int wave = tid >> 6;
    const int lane = tid & 63;
    const int lrow = lane >> 3;                      // 0..7
    const int lxor = ((lane & 7) ^ lrow) * 16;       // inverse-swizzled src unit

    const char* aggw_b = (const char*)aggw + (size_t)b * 9 * COUT * CIN * 2;
    const char* xt_b   = (const char*)xt   + (size_t)b * HW * CIN * 2;
    const char* zb     = (const char*)zbuf;

    // Per-issue fixed offsets. Issue j covers rows j*32 + wave*8 + lrow.
    int aoff[4];
    int boff[4], bh[4], bw[4], bval[4];
    #pragma unroll
    for (int j = 0; j < 4; ++j) {
        const int rowl = j * 32 + wave * 8 + lrow;
        aoff[j] = (o0 + rowl) * 512 + lxor;
        const int p = p0 + rowl;
        bh[j]   = p / 56;
        bw[j]   = p % 56;
        bval[j] = (p < HW);
        boff[j] = p * 512 + lxor;        // (h*56+w)*CIN*2 + swizzled unit
    }

    floatx4 acc[4][4];
    #pragma unroll
    for (int mi = 0; mi < 4; ++mi)
        #pragma unroll
        for (int ni = 0; ni < 4; ++ni)
            #pragma unroll
            for (int i = 0; i < 4; ++i) acc[mi][ni][i] = 0.f;

    const int row_base = (wave >> 1) * 64;
    const int col_base = (wave & 1) * 64;
    const int m_off    = lane & 15;
    const int q        = lane >> 4;         // 0..3 (8-element k-group)
    const int sx       = m_off & 7;         // read-side swizzle key

    for (int kt = 0; kt < 36; ++kt) {
        const int rs = kt >> 2;
        const int c0 = (kt & 3) * 64;
        const int dh = rs / 3 - 1;
        const int dw = rs % 3 - 1;

        const int a_kt = rs * (COUT * CIN * 2) + c0 * 2;   // uniform
        const int b_kt = (dh * 56 + dw) * 512 + c0 * 2;    // uniform

        #pragma unroll
        for (int j = 0; j < 4; ++j) {
            async_copy16(aggw_b + (size_t)(aoff[j] + a_kt),
                         &As[(j * 32 + wave * 8) * 64]);
        }
        #pragma unroll
        for (int j = 0; j < 4; ++j) {
            const int h2 = bh[j] + dh;
            const int w2 = bw[j] + dw;
            const bool ok = bval[j] && ((unsigned)h2 < 56u) && ((unsigned)w2 < 56u);
            const char* src = ok ? (xt_b + (size_t)(boff[j] + b_kt))
                                 : (zb + lxor);
            async_copy16(src, &Bs[(j * 32 + wave * 8) * 64]);
        }
        __syncthreads();   // drains vmcnt(0): LDS tiles ready

        #pragma unroll
        for (int ks = 0; ks < 2; ++ks) {
            short8 af[4], bf[4];
            #pragma unroll
            for (int mi = 0; mi < 4; ++mi)
                af[mi] = *(const short8*)((const char*)As
                          + (row_base + mi * 16 + m_off) * 128
                          + (((ks * 4 + q) ^ sx) * 16));
            #pragma unroll
            for (int ni = 0; ni < 4; ++ni)
                bf[ni] = *(const short8*)((const char*)Bs
                          + (col_base + ni * 16 + m_off) * 128
                          + (((ks * 4 + q) ^ sx) * 16));
            #pragma unroll
            for (int mi = 0; mi < 4; ++mi)
                #pragma unroll
                for (int ni = 0; ni < 4; ++ni)
                    acc[mi][ni] = __builtin_amdgcn_mfma_f32_16x16x32_bf16(
                        af[mi], bf[ni], acc[mi][ni], 0, 0, 0);
        }
        __syncthreads();   // all waves done reading before next stage
    }

    // Epilogue: C/D layout col = lane&15, row = (lane>>4)*4 + i
    float* outb = out + (size_t)b * COUT * HW;
    const int g4 = (lane >> 4) * 4;
    #pragma unroll
    for (int mi = 0; mi < 4; ++mi) {
        #pragma unroll
        for (int i = 0; i < 4; ++i) {
            const int o = o0 + row_base + mi * 16 + g4 + i;
            const float bv = aggb[b * COUT + o];
            #pragma unroll
            for (int ni = 0; ni < 4; ++ni) {
                const int p = p0 + col_base + ni * 16 + m_off;
                if (p < HW) outb[(size_t)o * HW + p] = acc[mi][ni][i] + bv;
            }
        }
    }
}

// ---------------------------------------------------------------------------
// Launch
// ---------------------------------------------------------------------------
extern "C" void kernel_launch(void* const* d_in, const int* in_sizes, int n_in,
                              void* d_out, int out_size, void* d_ws, size_t ws_size,
                              hipStream_t stream) {
    const float* x      = (const float*)d_in[0];
    const float* weight = (const float*)d_in[1];
    const float* bias   = (const float*)d_in[2];
    const float* fc1w   = (const float*)d_in[3];
    const float* fc1b   = (const float*)d_in[4];
    const float* fc2w   = (const float*)d_in[5];
    const float* fc2b   = (const float*)d_in[6];
    float* out = (float*)d_out;

    char* ws = (char*)d_ws;
    // workspace layout (all 256 B aligned)
    unsigned short* xt     = (unsigned short*)(ws);              // 51,380,224 B
    unsigned short* aggw   = (unsigned short*)(ws + 51380224);   // 37,748,736 B
    float*          pooled = (float*)(ws + 89128960);            //     32,768 B
    float*          att    = (float*)(ws + 89161728);            //        512 B
    float*          aggb   = (float*)(ws + 89162240);            //     32,768 B
    unsigned short* zbuf   = (unsigned short*)(ws + 89195008);   //        256 B

    hipMemsetAsync((void*)pooled, 0, 32768, stream);
    hipMemsetAsync((void*)zbuf,   0, 256,   stream);

    transpose_pool_kernel<<<BB * HH, 256, 0, stream>>>(x, xt, pooled);
    attn_kernel<<<BB, 64, 0, stream>>>(pooled, fc1w, fc1b, fc2w, fc2b, att);
    aggw_kernel<<<BB * COUT, 256, 0, stream>>>(weight, bias, att, aggw, aggb);
    conv_gemm_kernel<<<BB * 2 * 25, 256, 0, stream>>>(xt, aggw, aggb, zbuf, out);
}

// Round 3
// 367.607 us; speedup vs baseline: 1.3246x; 1.0969x over previous
//
#include <hip/hip_runtime.h>
#include <hip/hip_bf16.h>
#include <stdint.h>

// Problem constants
#define BB   32
#define CIN  256
#define COUT 256
#define HH   56
#define WW   56
#define HW   3136           // 56*56
#define KEXP 4
#define HP   58             // padded spatial (1-px zero halo)

typedef __attribute__((ext_vector_type(8))) short  short8;
typedef __attribute__((ext_vector_type(4))) float  floatx4;

__device__ __forceinline__ unsigned short f2bf(float f) {
    uint32_t u = __float_as_uint(f);
    u = (u + 0x7fffu + ((u >> 16) & 1u)) >> 16;
    return (unsigned short)u;
}
__device__ __forceinline__ float bf2f(unsigned short s) {
    return __uint_as_float(((uint32_t)s) << 16);
}
__device__ __forceinline__ uint32_t pack2(float a, float b) {
    return (uint32_t)f2bf(a) | ((uint32_t)f2bf(b) << 16);
}

__device__ __forceinline__ void async_copy16(const void* gsrc, void* ldst) {
    __builtin_amdgcn_global_load_lds(
        (const __attribute__((address_space(1))) unsigned int*)gsrc,
        (__attribute__((address_space(3))) unsigned int*)ldst, 16, 0, 0);
}

// ---------------------------------------------------------------------------
// Kernel T: NCHW fp32 -> padded NHWC bf16, plus per-(b,h) pool partials.
// grid: B*H blocks, 256 threads. No atomics: partial[b][h][c] written once.
// Halo: each block zeros w'=0/57 of its row; h==0 blocks zero rows 0 and 57.
// ---------------------------------------------------------------------------
__global__ __launch_bounds__(256) void transpose_pool_kernel(
    const float* __restrict__ x,          // [B][CIN][H][W]
    unsigned short* __restrict__ xt,      // [B][58][58][CIN] bf16, halo zero
    float* __restrict__ partial)          // [B][H][CIN] row sums
{
    __shared__ unsigned short tile[CIN * 62];   // [c][w] stride 62: bank-safe
    const int bx  = blockIdx.x;
    const int b   = bx / HH;
    const int h   = bx % HH;
    const int tid = threadIdx.x;

    const float* xb = x + (size_t)b * CIN * HW + h * WW;

    for (int i = tid; i < CIN * 14; i += 256) {
        const int c  = i / 14;
        const int wv = i % 14;
        const float4 v = *(const float4*)(xb + (size_t)c * HW + wv * 4);
        uint32_t* p = (uint32_t*)&tile[c * 62 + wv * 4];
        p[0] = pack2(v.x, v.y);
        p[1] = pack2(v.z, v.w);
    }
    __syncthreads();

    // per-channel row sum (c = tid)
    {
        float s = 0.f;
        #pragma unroll 8
        for (int i = 0; i < WW; ++i) s += bf2f(tile[tid * 62 + i]);
        partial[((size_t)b * HH + h) * CIN + tid] = s;
    }

    // padded NHWC write, 2 channels per lane (4 B stores)
    unsigned short* row = xt + (((size_t)b * HP + (h + 1)) * HP) * CIN;
    for (int j = tid; j < WW * 128; j += 256) {
        const int w  = j >> 7;
        const int c2 = (j & 127) * 2;
        const uint32_t v = (uint32_t)tile[c2 * 62 + w]
                         | ((uint32_t)tile[(c2 + 1) * 62 + w] << 16);
        *(uint32_t*)&row[(w + 1) * CIN + c2] = v;
    }

    // halo: w'=0 and w'=57 of this row
    if (tid < 128) {
        ((uint32_t*)&row[0])[tid]          = 0u;
        ((uint32_t*)&row[57 * CIN])[tid]   = 0u;
    }
    // halo: full rows h'=0 and h'=57 (only h==0 blocks)
    if (h == 0) {
        uint32_t* r0  = (uint32_t*)(xt + ((size_t)b * HP + 0)  * HP * CIN);
        uint32_t* r57 = (uint32_t*)(xt + ((size_t)b * HP + 57) * HP * CIN);
        for (int i = tid; i < HP * 128; i += 256) { r0[i] = 0u; r57[i] = 0u; }
    }
}

// ---------------------------------------------------------------------------
// Kernel A: pool-partial reduce + attention MLP + softmax -> att[B][K]
// grid: B blocks x 256 threads
// ---------------------------------------------------------------------------
__global__ __launch_bounds__(256) void attn_kernel(
    const float* __restrict__ partial,  // [B][H][CIN]
    const float* __restrict__ fc1w,     // [K][CIN]
    const float* __restrict__ fc1b,     // [K]
    const float* __restrict__ fc2w,     // [K][K]
    const float* __restrict__ fc2b,     // [K]
    float* __restrict__ att)            // [B][K]
{
    __shared__ float pl[CIN];
    const int b   = blockIdx.x;
    const int tid = threadIdx.x;

    float s = 0.f;
    const float* pp = partial + (size_t)b * HH * CIN + tid;
    #pragma unroll 8
    for (int h = 0; h < HH; ++h) s += pp[h * CIN];
    pl[tid] = s * (1.0f / (float)HW);
    __syncthreads();

    if (tid < 64) {
        const int lane = tid;
        float sk[KEXP] = {0.f, 0.f, 0.f, 0.f};
        #pragma unroll
        for (int c0 = 0; c0 < CIN; c0 += 64) {
            const float p = pl[c0 + lane];
            #pragma unroll
            for (int k = 0; k < KEXP; ++k) sk[k] += p * fc1w[k * CIN + c0 + lane];
        }
        #pragma unroll
        for (int off = 32; off > 0; off >>= 1) {
            #pragma unroll
            for (int k = 0; k < KEXP; ++k) sk[k] += __shfl_down(sk[k], off);
        }
        if (lane == 0) {
            float a[KEXP];
            #pragma unroll
            for (int k = 0; k < KEXP; ++k) a[k] = fmaxf(sk[k] + fc1b[k], 0.f);
            float z[KEXP], m = -1e30f;
            #pragma unroll
            for (int j = 0; j < KEXP; ++j) {
                float t = fc2b[j];
                #pragma unroll
                for (int k = 0; k < KEXP; ++k) t += a[k] * fc2w[j * KEXP + k];
                z[j] = t;
                m = fmaxf(m, t);
            }
            float den = 0.f;
            #pragma unroll
            for (int j = 0; j < KEXP; ++j) { z[j] = expf(z[j] - m); den += z[j]; }
            const float inv = 1.0f / den;
            #pragma unroll
            for (int j = 0; j < KEXP; ++j) att[b * KEXP + j] = z[j] * inv;
        }
    }
}

// ---------------------------------------------------------------------------
// Kernel W: aggregate expert weights -> agg_w[b][rs][o][c] (bf16), agg_b[b][o]
// grid: COUT*4 blocks: o = bx>>2, b-quarter = bx&3 (8 samples each).
// Weights for this o held in registers across the whole b-loop: weight HBM
// reads drop from 302 MB (one read per (b,o)) to 38 MB total.
// ---------------------------------------------------------------------------
__global__ __launch_bounds__(256) void aggw_kernel(
    const float* __restrict__ weight,   // [K][COUT][CIN][3][3]
    const float* __restrict__ bias,     // [K][COUT]
    const float* __restrict__ att,      // [B][K]
    unsigned short* __restrict__ aggw,  // [B][9][COUT][CIN] bf16
    float* __restrict__ aggb)           // [B][COUT]
{
    __shared__ float accw[CIN * 9];     // staging for (c,rs)->(rs,c) transpose
    const int bx  = blockIdx.x;
    const int o   = bx >> 2;
    const int b0  = (bx & 3) * 8;
    const int tid = threadIdx.x;

    // thread t holds weight-flat[j*256 + t] for each expert (identity staging:
    // flat index c*9+rs is covered bijectively by (j,t))
    float wreg[KEXP][9];
    #pragma unroll
    for (int k = 0; k < KEXP; ++k) {
        const float* wk = weight + (size_t)(k * COUT + o) * (CIN * 9);
        #pragma unroll
        for (int j = 0; j < 9; ++j) wreg[k][j] = wk[j * 256 + tid];
    }
    float bvals[KEXP];
    #pragma unroll
    for (int k = 0; k < KEXP; ++k) bvals[k] = bias[k * COUT + o];

    for (int bi = 0; bi < 8; ++bi) {
        const int b = b0 + bi;
        float av[KEXP];
        #pragma unroll
        for (int k = 0; k < KEXP; ++k) av[k] = att[b * KEXP + k];

        __syncthreads();   // previous iteration's accw reads complete
        #pragma unroll
        for (int j = 0; j < 9; ++j) {
            float r = 0.f;
            #pragma unroll
            for (int k = 0; k < KEXP; ++k) r += av[k] * wreg[k][j];
            accw[j * 256 + tid] = r;   // accw[flat] mirrors weight-flat layout
        }
        __syncthreads();

        // element (c, rs) = accw[c*9 + rs]; write [rs][c] packed pairs
        for (int i = tid; i < 9 * 128; i += 256) {
            const int j  = i >> 7;          // rs
            const int cp = (i & 127) * 2;   // channel pair
            const uint32_t v = pack2(accw[cp * 9 + j], accw[(cp + 1) * 9 + j]);
            *(uint32_t*)&aggw[(((size_t)b * 9 + j) * COUT + o) * CIN + cp] = v;
        }
        if (tid == 0) {
            float sb = 0.f;
            #pragma unroll
            for (int k = 0; k < KEXP; ++k) sb += av[k] * bvals[k];
            aggb[b * COUT + o] = sb;
        }
    }
}

// ---------------------------------------------------------------------------
// Kernel G: per-sample implicit-im2col GEMM (m97 structure)
// grid: B*2*25 = 1600 blocks, 256 threads (4 waves), XCD-affinity swizzle.
// Halo-padded xt: B staging is a single unconditional address add per copy.
// LDS XOR swizzle (write-side inverse on global src) -> 0 bank conflicts.
// ---------------------------------------------------------------------------
__global__ __launch_bounds__(256) void conv_gemm_kernel(
    const unsigned short* __restrict__ xt,    // [B][58][58][CIN] bf16 padded
    const unsigned short* __restrict__ aggw,  // [B][9][COUT][CIN] bf16
    const float* __restrict__ aggb,           // [B][COUT]
    float* __restrict__ out)                  // [B][COUT][HW]
{
    __shared__ unsigned short As[128 * 64];   // [o_local][c] 16 KB, swizzled
    __shared__ unsigned short Bs[128 * 64];   // [p_local][c] 16 KB, swizzled

    const int bx   = blockIdx.x;
    const int slot = bx >> 3;          // 0..199 within an XCD
    const int xcd  = bx & 7;
    const int b    = xcd + 8 * (slot / 50);
    const int rr   = slot % 50;
    const int pt   = rr >> 1;
    const int ot   = rr & 1;
    const int o0   = ot * 128;
    const int p0   = pt * 128;

    const int tid  = threadIdx.x;
    const int wave = tid >> 6;
    const int lane = tid & 63;
    const int lrow = lane >> 3;                      // 0..7
    const int lxor = ((lane & 7) ^ lrow) * 16;       // inverse-swizzled unit

    const char* aggw_b = (const char*)aggw + (size_t)b * 9 * COUT * CIN * 2;
    const char* xt_b   = (const char*)xt   + (size_t)b * HP * HP * CIN * 2;

    // Prologue-only address setup; no per-iteration conditionals.
    int aoff[4], boff[4];
    #pragma unroll
    for (int j = 0; j < 4; ++j) {
        const int rowl = j * 32 + wave * 8 + lrow;
        aoff[j] = (o0 + rowl) * 512 + lxor;
        const int p  = p0 + rowl;
        const int pv = (p < HW) ? p : 0;           // invalid rows -> pixel 0
        const int h  = pv / 56;
        const int w  = pv % 56;
        boff[j] = ((h + 1) * HP + (w + 1)) * 512 + lxor;
    }

    floatx4 acc[4][4];
    #pragma unroll
    for (int mi = 0; mi < 4; ++mi)
        #pragma unroll
        for (int ni = 0; ni < 4; ++ni)
            #pragma unroll
            for (int i = 0; i < 4; ++i) acc[mi][ni][i] = 0.f;

    const int row_base = (wave >> 1) * 64;
    const int col_base = (wave & 1) * 64;
    const int m_off    = lane & 15;
    const int q        = lane >> 4;
    const int sx       = m_off & 7;

    for (int kt = 0; kt < 36; ++kt) {
        const int rs = kt >> 2;
        const int c0 = (kt & 3) * 64;
        const int dh = rs / 3 - 1;
        const int dw = rs % 3 - 1;

        const int a_kt = rs * (COUT * CIN * 2) + c0 * 2;        // uniform
        const int b_kt = (dh * HP + dw) * 512 + c0 * 2;         // uniform

        #pragma unroll
        for (int j = 0; j < 4; ++j)
            async_copy16(aggw_b + (size_t)(aoff[j] + a_kt),
                         &As[(j * 32 + wave * 8) * 64]);
        #pragma unroll
        for (int j = 0; j < 4; ++j)
            async_copy16(xt_b + (size_t)(boff[j] + b_kt),
                         &Bs[(j * 32 + wave * 8) * 64]);
        __syncthreads();

        #pragma unroll
        for (int ks = 0; ks < 2; ++ks) {
            short8 af[4], bf[4];
            #pragma unroll
            for (int mi = 0; mi < 4; ++mi)
                af[mi] = *(const short8*)((const char*)As
                          + (row_base + mi * 16 + m_off) * 128
                          + (((ks * 4 + q) ^ sx) * 16));
            #pragma unroll
            for (int ni = 0; ni < 4; ++ni)
                bf[ni] = *(const short8*)((const char*)Bs
                          + (col_base + ni * 16 + m_off) * 128
                          + (((ks * 4 + q) ^ sx) * 16));
            #pragma unroll
            for (int mi = 0; mi < 4; ++mi)
                #pragma unroll
                for (int ni = 0; ni < 4; ++ni)
                    acc[mi][ni] = __builtin_amdgcn_mfma_f32_16x16x32_bf16(
                        af[mi], bf[ni], acc[mi][ni], 0, 0, 0);
        }
        __syncthreads();
    }

    // Epilogue: C/D layout col = lane&15, row = (lane>>4)*4 + i
    float* outb = out + (size_t)b * COUT * HW;
    const int g4 = (lane >> 4) * 4;
    #pragma unroll
    for (int mi = 0; mi < 4; ++mi) {
        #pragma unroll
        for (int i = 0; i < 4; ++i) {
            const int o = o0 + row_base + mi * 16 + g4 + i;
            const float bv = aggb[b * COUT + o];
            #pragma unroll
            for (int ni = 0; ni < 4; ++ni) {
                const int p = p0 + col_base + ni * 16 + m_off;
                if (p < HW) outb[(size_t)o * HW + p] = acc[mi][ni][i] + bv;
            }
        }
    }
}

// ---------------------------------------------------------------------------
// Launch
// ---------------------------------------------------------------------------
extern "C" void kernel_launch(void* const* d_in, const int* in_sizes, int n_in,
                              void* d_out, int out_size, void* d_ws, size_t ws_size,
                              hipStream_t stream) {
    const float* x      = (const float*)d_in[0];
    const float* weight = (const float*)d_in[1];
    const float* bias   = (const float*)d_in[2];
    const float* fc1w   = (const float*)d_in[3];
    const float* fc1b   = (const float*)d_in[4];
    const float* fc2w   = (const float*)d_in[5];
    const float* fc2b   = (const float*)d_in[6];
    float* out = (float*)d_out;

    char* ws = (char*)d_ws;
    // workspace layout (256 B aligned)
    unsigned short* xt      = (unsigned short*)(ws);              // 55,115,776 B
    unsigned short* aggw    = (unsigned short*)(ws + 55115776);   // 37,748,736 B
    float*          partial = (float*)(ws + 92864512);            //  1,835,008 B
    float*          att     = (float*)(ws + 94699520);            //        512 B
    float*          aggb    = (float*)(ws + 94700032);            //     32,768 B

    transpose_pool_kernel<<<BB * HH, 256, 0, stream>>>(x, xt, partial);
    attn_kernel<<<BB, 256, 0, stream>>>(partial, fc1w, fc1b, fc2w, fc2b, att);
    aggw_kernel<<<COUT * 4, 256, 0, stream>>>(weight, bias, att, aggw, aggb);
    conv_gemm_kernel<<<BB * 2 * 25, 256, 0, stream>>>(xt, aggw, aggb, out);
}